// Round 1
// baseline (462.532 us; speedup 1.0000x reference)
//
#include <hip/hip_runtime.h>
#include <hip/hip_bf16.h>
#include <stdint.h>

typedef unsigned short bf16_t;
typedef __attribute__((ext_vector_type(8))) short short8;
typedef __attribute__((ext_vector_type(4))) float f32x4;

#define BM 128
#define BN 128
#define BK 32

__device__ __forceinline__ bf16_t f2b(float f) {
    union { float f; uint32_t u; } v; v.f = f;
    uint32_t u = v.u;
    return (bf16_t)((u + 0x7FFFu + ((u >> 16) & 1u)) >> 16);
}

__global__ __launch_bounds__(256) void cvt_f32_bf16(const float* __restrict__ in,
                                                    bf16_t* __restrict__ out, int n4) {
    int i = blockIdx.x * blockDim.x + threadIdx.x;
    if (i >= n4) return;
    float4 f = ((const float4*)in)[i];
    ushort4 o;
    o.x = f2b(f.x); o.y = f2b(f.y); o.z = f2b(f.z); o.w = f2b(f.w);
    ((ushort4*)out)[i] = o;
}

__device__ __forceinline__ void lds_dma16(const void* g, void* l) {
    __builtin_amdgcn_global_load_lds(
        (const __attribute__((address_space(1))) void*)g,
        (__attribute__((address_space(3))) void*)l, 16, 0, 0);
}

// C = A (M x K row-major, lda) * B^T (B stored N x K row-major, ldb) + epilogue
// MODE 0: out bf16 row-major, val=(acc+bias[col])*scale          (Q/K proj)
// MODE 2: out bf16 transposed Vt[b][col][s], val=acc+bias[col]   (V proj)
// MODE 3: out bf16 row-major, val=sigmoid(acc+biasmat[row][col]) (scores)
// MODE 4: out f32 row-major, val=acc                             (PV -> d_out)
template <int MODE>
__global__ __launch_bounds__(256)
void gemm_bt(const bf16_t* __restrict__ Ag, int lda, int64_t sAz,
             const bf16_t* __restrict__ Bg, int ldb, int64_t sBz,
             const float* __restrict__ bias,
             void* __restrict__ outp, int64_t sOz, int ldo,
             int K, float scale)
{
    __shared__ bf16_t lsA[BM * BK];
    __shared__ bf16_t lsB[BN * BK];

    const int tid  = threadIdx.x;
    const int lane = tid & 63;
    const int w    = tid >> 6;
    const int wm   = w & 1, wn = w >> 1;
    const int ll   = lane & 15;
    const int quad = lane >> 4;

    const int m0 = blockIdx.y * BM;
    const int n0 = blockIdx.x * BN;
    const int z  = blockIdx.z;

    const bf16_t* A = Ag + (size_t)z * sAz;
    const bf16_t* B = Bg + (size_t)z * sBz;

    f32x4 acc[4][4];
#pragma unroll
    for (int i = 0; i < 4; i++)
#pragma unroll
        for (int j = 0; j < 4; j++) acc[i][j] = (f32x4){0.f, 0.f, 0.f, 0.f};

    for (int k0 = 0; k0 < K; k0 += BK) {
        // stage 128x32 bf16 A and B tiles: 512 chunks of 16B each,
        // 4 waves x 64 lanes x 2 rounds; LDS dest = wave-uniform base + lane*16
#pragma unroll
        for (int c = 0; c < 2; ++c) {
            const int base = (c * 4 + w) * 64;
            const int idx  = base + lane;
            const int row  = idx >> 2;
            const int kc   = (idx & 3) << 3;
            lds_dma16(A + (size_t)(m0 + row) * lda + k0 + kc, (char*)lsA + base * 16);
            lds_dma16(B + (size_t)(n0 + row) * ldb + k0 + kc, (char*)lsB + base * 16);
        }
        __syncthreads();

        short8 af[4], bf[4];
#pragma unroll
        for (int i = 0; i < 4; i++) {
            af[i] = *(const short8*)(lsA + (wm * 64 + i * 16 + ll) * BK + quad * 8);
            bf[i] = *(const short8*)(lsB + (wn * 64 + i * 16 + ll) * BK + quad * 8);
        }
#pragma unroll
        for (int i = 0; i < 4; i++)
#pragma unroll
            for (int j = 0; j < 4; j++)
                acc[i][j] = __builtin_amdgcn_mfma_f32_16x16x32_bf16(af[i], bf[j], acc[i][j], 0, 0, 0);
        __syncthreads();
    }

    // epilogue: C/D layout col=lane&15, row=quad*4+reg
#pragma unroll
    for (int i = 0; i < 4; i++) {
#pragma unroll
        for (int j = 0; j < 4; j++) {
            const int col  = n0 + wn * 64 + j * 16 + ll;
            const int rowb = m0 + wm * 64 + i * 16 + quad * 4;
            f32x4 a = acc[i][j];
            if (MODE == 0) {
                const float bv = bias[col];
                bf16_t* o = (bf16_t*)outp;
#pragma unroll
                for (int r = 0; r < 4; r++)
                    o[(size_t)(rowb + r) * ldo + col] = f2b((a[r] + bv) * scale);
            } else if (MODE == 2) {
                const float bv = bias[col];
                bf16_t* o = (bf16_t*)outp;
                const int b = rowb >> 12;
                const int s = rowb & 4095;
                ushort4 pk;
                pk.x = f2b(a[0] + bv);
                pk.y = f2b(a[1] + bv);
                pk.z = f2b(a[2] + bv);
                pk.w = f2b(a[3] + bv);
                *(ushort4*)(o + ((size_t)b * 512 + col) * 4096 + s) = pk;
            } else if (MODE == 3) {
                bf16_t* o = (bf16_t*)outp + (size_t)z * sOz;
#pragma unroll
                for (int r = 0; r < 4; r++) {
                    const int row = rowb + r;
                    const float v = a[r] + bias[(size_t)row * 4096 + col];
                    o[(size_t)row * ldo + col] = f2b(1.f / (1.f + __expf(-v)));
                }
            } else if (MODE == 4) {
                float* o = (float*)outp + (size_t)z * sOz;
#pragma unroll
                for (int r = 0; r < 4; r++)
                    o[(size_t)(rowb + r) * ldo + col] = a[r];
            }
        }
    }
}

extern "C" void kernel_launch(void* const* d_in, const int* in_sizes, int n_in,
                              void* d_out, int out_size, void* d_ws, size_t ws_size,
                              hipStream_t stream) {
    (void)in_sizes; (void)n_in; (void)out_size; (void)ws_size;
    const float* x    = (const float*)d_in[0];
    const float* bias = (const float*)d_in[1];
    const float* Wq_w = (const float*)d_in[2];
    const float* Wq_b = (const float*)d_in[3];
    const float* Wk_w = (const float*)d_in[4];
    const float* Wk_b = (const float*)d_in[5];
    const float* Wv_w = (const float*)d_in[6];
    const float* Wv_b = (const float*)d_in[7];
    float* out = (float*)d_out;

    // workspace layout (bf16 elements)
    bf16_t* Xb = (bf16_t*)d_ws;                    // 16384 x 512
    bf16_t* Wb = Xb + (size_t)16384 * 512;         // 3 x 512 x 512
    bf16_t* Qb = Wb + (size_t)3 * 512 * 512;       // 16384 x 512 (pre-scaled by 1/sqrt(D))
    bf16_t* Kb = Qb + (size_t)16384 * 512;         // 16384 x 512
    bf16_t* Vt = Kb + (size_t)16384 * 512;         // 4 x 512 x 4096 (transposed V)
    bf16_t* P  = Vt + (size_t)16384 * 512;         // 4 x 4096 x 4096
    // total ~203 MB

    cvt_f32_bf16<<<8192, 256, 0, stream>>>(x, Xb, 2097152);
    cvt_f32_bf16<<<256, 256, 0, stream>>>(Wq_w, Wb, 65536);
    cvt_f32_bf16<<<256, 256, 0, stream>>>(Wk_w, Wb + 262144, 65536);
    cvt_f32_bf16<<<256, 256, 0, stream>>>(Wv_w, Wb + 524288, 65536);

    const float inv = 0.044194173824159216f;  // 1/sqrt(512)

    // projections: M=16384, N=512, K=512
    gemm_bt<0><<<dim3(4, 128, 1), 256, 0, stream>>>(Xb, 512, 0, Wb, 512, 0,
                                                    Wq_b, Qb, 0, 512, 512, inv);
    gemm_bt<0><<<dim3(4, 128, 1), 256, 0, stream>>>(Xb, 512, 0, Wb + 262144, 512, 0,
                                                    Wk_b, Kb, 0, 512, 512, 1.0f);
    gemm_bt<2><<<dim3(4, 128, 1), 256, 0, stream>>>(Xb, 512, 0, Wb + 524288, 512, 0,
                                                    Wv_b, Vt, 0, 0, 512, 1.0f);
    // scores + sigmoid: per batch M=N=4096, K=512
    gemm_bt<3><<<dim3(32, 32, 4), 256, 0, stream>>>(Qb, 512, (int64_t)4096 * 512,
                                                    Kb, 512, (int64_t)4096 * 512,
                                                    bias, P, (int64_t)4096 * 4096, 4096,
                                                    512, 1.0f);
    // out = P * V: per batch M=4096, N=512, K=4096
    gemm_bt<4><<<dim3(4, 32, 4), 256, 0, stream>>>(P, 4096, (int64_t)4096 * 4096,
                                                   Vt, 4096, (int64_t)512 * 4096,
                                                   nullptr, out, (int64_t)4096 * 512, 512,
                                                   4096, 1.0f);
}